// Round 1
// baseline (341.592 us; speedup 1.0000x reference)
//
#include <hip/hip_runtime.h>
#include <hip/hip_bf16.h>

constexpr int TTOK  = 16384;   // B*S = 8*2048
constexpr int DDIM  = 512;
constexpr int FFDIM = 2048;
constexpr int NEXP  = 8;
constexpr int GB_TOK = 16;             // tokens per gate/scatter block
constexpr int NGB    = TTOK / GB_TOK;  // 1024
constexpr int MAXTILES = TTOK / 128 + NEXP;  // 136: worst-case M-tiles over all experts

typedef __attribute__((ext_vector_type(8))) short short8_t;
typedef __attribute__((ext_vector_type(4))) float f32x4_t;

__device__ __forceinline__ unsigned short f2bf(float f) {
    union { float f; unsigned u; } v; v.f = f;
    return (unsigned short)((v.u + 0x7fffu + ((v.u >> 16) & 1u)) >> 16);  // RNE
}

__device__ __forceinline__ void gl_lds16(const void* g, void* l) {
    __builtin_amdgcn_global_load_lds(
        (const __attribute__((address_space(1))) void*)g,
        (__attribute__((address_space(3))) void*)l,
        16, 0, 0);
}

// ---------------- transpose + fp32->bf16 cast:  src [E][R][C] f32 -> dst [E][C][R] bf16
// (R5 version: 32x32 tiles, 4 KB LDS, high occupancy — measured-good)
__global__ __launch_bounds__(256) void transpose_cvt2(const float* __restrict__ W1,
                                                      const float* __restrict__ W2,
                                                      unsigned short* __restrict__ W1T,
                                                      unsigned short* __restrict__ W2T) {
    __shared__ float tile[32][33];
    int z = blockIdx.z;
    bool isW2 = z >= NEXP;
    int e = isW2 ? z - NEXP : z;
    int R = isW2 ? FFDIM : DDIM;
    int C = isW2 ? DDIM : FFDIM;
    int tilesC = C / 32;
    int t = blockIdx.x;                    // 1024 tiles either way
    int c0 = (t % tilesC) * 32;
    int r0 = (t / tilesC) * 32;
    const float* s = (isW2 ? W2 : W1) + (size_t)e * DDIM * FFDIM;
    unsigned short* d = (isW2 ? W2T : W1T) + (size_t)e * DDIM * FFDIM;
    int tx = threadIdx.x & 31, ty = threadIdx.x >> 5;   // 32 x 8
    #pragma unroll
    for (int i = 0; i < 4; i++)
        tile[ty + 8 * i][tx] = s[(size_t)(r0 + ty + 8 * i) * C + c0 + tx];
    __syncthreads();
    #pragma unroll
    for (int i = 0; i < 4; i++)
        d[(size_t)(c0 + ty + 8 * i) * R + r0 + tx] = f2bf(tile[tx][ty + 8 * i]);
}

// ---------------- gating: Wg in registers, f64 accum, 1024 blocks x 16 tokens (R5 version)
__global__ __launch_bounds__(256) void gate_kernel(const float* __restrict__ x,
                                                   const float* __restrict__ Wg,
                                                   const float* __restrict__ bg,
                                                   int* __restrict__ route,
                                                   float* __restrict__ pmax,
                                                   int* __restrict__ blockCounts) {
    __shared__ int cnt[NEXP];
    __shared__ float bgs[NEXP];
    int tid = threadIdx.x;
    if (tid < NEXP) { cnt[tid] = 0; bgs[tid] = bg[tid]; }
    __syncthreads();
    int wave = tid >> 6, lane = tid & 63;
    float w[8][8];
    #pragma unroll
    for (int jj = 0; jj < 8; jj++) {
        float4 a = *(const float4*)(Wg + (size_t)(lane * 8 + jj) * NEXP);
        float4 b = *(const float4*)(Wg + (size_t)(lane * 8 + jj) * NEXP + 4);
        w[jj][0] = a.x; w[jj][1] = a.y; w[jj][2] = a.z; w[jj][3] = a.w;
        w[jj][4] = b.x; w[jj][5] = b.y; w[jj][6] = b.z; w[jj][7] = b.w;
    }
    int tbase = blockIdx.x * GB_TOK + wave * 4;
    for (int it = 0; it < 4; it++) {
        int t = tbase + it;
        float4 xa = *(const float4*)(x + (size_t)t * DDIM + lane * 8);
        float4 xb = *(const float4*)(x + (size_t)t * DDIM + lane * 8 + 4);
        float xs[8] = {xa.x, xa.y, xa.z, xa.w, xb.x, xb.y, xb.z, xb.w};
        double acc[NEXP];
        #pragma unroll
        for (int e = 0; e < NEXP; e++) acc[e] = 0.0;
        #pragma unroll
        for (int jj = 0; jj < 8; jj++) {
            double xv = (double)xs[jj];
            #pragma unroll
            for (int e = 0; e < NEXP; e++) acc[e] += xv * (double)w[jj][e];
        }
        #pragma unroll
        for (int off = 32; off > 0; off >>= 1) {
            #pragma unroll
            for (int e = 0; e < NEXP; e++) acc[e] += __shfl_down(acc[e], off);
        }
        if (lane == 0) {
            double l[NEXP];
            #pragma unroll
            for (int e = 0; e < NEXP; e++) l[e] = acc[e] + (double)bgs[e];
            int r = 0; double lm = l[0];
            #pragma unroll
            for (int e = 1; e < NEXP; e++) if (l[e] > lm) { lm = l[e]; r = e; }
            double s = 0.0;
            #pragma unroll
            for (int e = 0; e < NEXP; e++) s += exp(l[e] - lm);
            route[t] = r;
            pmax[t] = (float)(1.0 / s);
            atomicAdd(&cnt[r], 1);
        }
    }
    __syncthreads();
    if (tid < NEXP) blockCounts[blockIdx.x * NEXP + tid] = cnt[tid];
}

// ---------------- single-block scan (1024 thr) -> stable counting-sort offsets + tile lists
__global__ __launch_bounds__(1024) void scan_kernel(const int* __restrict__ blockCounts,
                                                    int* __restrict__ blockOffsets,
                                                    int* __restrict__ segPrefix,
                                                    int* __restrict__ tilePrefix) {
    __shared__ int sc[NGB][NEXP];
    __shared__ int base[NEXP + 1];
    int b = threadIdx.x;
    int c[NEXP];
    #pragma unroll
    for (int e = 0; e < NEXP; e++) { c[e] = blockCounts[b * NEXP + e]; sc[b][e] = c[e]; }
    __syncthreads();
    for (int off = 1; off < NGB; off <<= 1) {
        int t[NEXP];
        if (b >= off) {
            #pragma unroll
            for (int e = 0; e < NEXP; e++) t[e] = sc[b - off][e];
        }
        __syncthreads();
        if (b >= off) {
            #pragma unroll
            for (int e = 0; e < NEXP; e++) sc[b][e] += t[e];
        }
        __syncthreads();
    }
    if (b == 0) {
        int s = 0;
        #pragma unroll
        for (int e = 0; e < NEXP; e++) { base[e] = s; s += sc[NGB - 1][e]; }
        base[NEXP] = s;
        for (int e = 0; e <= NEXP; e++) segPrefix[e] = base[e];
        int tp = 0;
        tilePrefix[0] = 0;
        for (int e = 0; e < NEXP; e++) {
            tp += (sc[NGB - 1][e] + 127) / 128;
            tilePrefix[e + 1] = tp;
        }
    }
    __syncthreads();
    #pragma unroll
    for (int e = 0; e < NEXP; e++)
        blockOffsets[b * NEXP + e] = base[e] + sc[b][e] - c[e];
}

// ---------------- scatter: Xs[dst(t)] = bf16(x[t] * pmax[t]), expert-sorted stable order
__global__ __launch_bounds__(256) void scatter_kernel(const float* __restrict__ x,
                                                      const int* __restrict__ route,
                                                      const float* __restrict__ pmax,
                                                      const int* __restrict__ blockOffsets,
                                                      unsigned short* __restrict__ Xs) {
    __shared__ int dstL[GB_TOK];
    __shared__ float pmL[GB_TOK];
    int tid = threadIdx.x;
    int bb = blockIdx.x;
    if (tid < GB_TOK) {
        int t = bb * GB_TOK + tid;
        int r = route[t];
        unsigned long long ltmask = (tid == 0) ? 0ull : ((~0ull) >> (64 - tid));
        int rank = 0;
        #pragma unroll
        for (int e = 0; e < NEXP; e++) {
            unsigned long long m = __ballot(r == e);
            if (r == e) rank = __popcll(m & ltmask);
        }
        dstL[tid] = blockOffsets[bb * NEXP + r] + rank;
        pmL[tid] = pmax[t];
    }
    __syncthreads();
    int wave = tid >> 6, lane = tid & 63;
    for (int rr = 0; rr < 4; rr++) {
        int rowl = wave * 4 + rr;
        int t = bb * GB_TOK + rowl;
        float pm = pmL[rowl];
        const float4* xr = (const float4*)(x + (size_t)t * DDIM) + lane * 2;
        float4 a = xr[0], b = xr[1];
        union { short8_t v; unsigned short s[8]; } o;
        o.s[0] = f2bf(a.x * pm); o.s[1] = f2bf(a.y * pm);
        o.s[2] = f2bf(a.z * pm); o.s[3] = f2bf(a.w * pm);
        o.s[4] = f2bf(b.x * pm); o.s[5] = f2bf(b.y * pm);
        o.s[6] = f2bf(b.z * pm); o.s[7] = f2bf(b.w * pm);
        *(short8_t*)(Xs + (size_t)dstL[rowl] * DDIM + lane * 8) = o.v;
    }
}

// ---------------- segmented GEMM, 128x128 tile, BK=64, DOUBLE-BUFFERED 2-phase pipeline.
// Per K-tile: issue next tile's global_load_lds FIRST, then ds_read+MFMA current tile,
// then ONE __syncthreads (its vmcnt(0)/lgkmcnt(0) drain certifies the staged buffer and
// protects read-before-overwrite). Staging latency hides under this tile's compute.
// + XCD-chunked m-tile swizzle (136 = 8*17): each XCD's A-panel chunk (2.2 MB @K=512)
// fits its 4 MB L2, so A re-reads across n-tiles become L2 hits.
template <bool RELU, typename OutT, int K, int N>
__global__ __launch_bounds__(256) void gemm_seg(const unsigned short* __restrict__ A,
                                                const unsigned short* __restrict__ Bt,
                                                const float* __restrict__ bias,
                                                OutT* __restrict__ C,
                                                const int* __restrict__ segPrefix,
                                                const int* __restrict__ tilePrefix) {
    int bx = blockIdx.x;
    bx = (bx & 7) * (MAXTILES / 8) + (bx >> 3);   // bijective XCD chunking (136 % 8 == 0)
    int t = bx;
    if (t >= tilePrefix[NEXP]) return;
    int e = 0;
    #pragma unroll
    for (int i = 1; i <= NEXP; i++) e += (t >= tilePrefix[i]) ? 1 : 0;
    int seg1 = segPrefix[e + 1];
    int m0 = segPrefix[e] + (t - tilePrefix[e]) * 128;
    int n0 = blockIdx.y * 128;

    // [buf][p(k-half)][128 rows][32 shorts], double-buffered over K-tiles: 32 KB each
    __shared__ unsigned short As[2 * 8192];
    __shared__ unsigned short Bs[2 * 8192];

    int tid = threadIdx.x, wave = tid >> 6, lane = tid & 63;
    const unsigned short* Bte = Bt + (size_t)e * N * K;

    int srow = lane >> 2;                                              // row within region
    int sg   = (lane & 3) ^ ((lane >> 2) & 3) ^ ((lane >> 4) & 3);     // swizzled src k-group
    int scol = sg * 8;

    f32x4_t acc[4][4];
    #pragma unroll
    for (int i = 0; i < 4; i++)
        #pragma unroll
        for (int j = 0; j < 4; j++) acc[i][j] = (f32x4_t){0.f, 0.f, 0.f, 0.f};

    int wm = (wave & 1) * 64;
    int wn = (wave >> 1) * 64;
    int frow = lane & 15;
    int gr = lane >> 4;
    int fswz = (gr ^ (frow & 3) ^ ((frow >> 2) & 3)) * 8;   // swizzled k-offset (shorts)

    int reg0 = wave * 2;
    int arow0 = m0 + reg0 * 16 + srow;
    arow0 = arow0 < TTOK ? arow0 : TTOK - 1;
    int arow1 = m0 + (reg0 + 1) * 16 + srow;
    arow1 = arow1 < TTOK ? arow1 : TTOK - 1;
    const unsigned short* aptr0 = A + (size_t)arow0 * K + scol;
    const unsigned short* aptr1 = A + (size_t)arow1 * K + scol;
    const unsigned short* bptr0 = Bte + (size_t)(n0 + reg0 * 16 + srow) * K + scol;
    const unsigned short* bptr1 = Bte + (size_t)(n0 + (reg0 + 1) * 16 + srow) * K + scol;

    auto stage = [&](int buf, int kc) {
        int lb = buf * 8192 + reg0 * 512;
        #pragma unroll
        for (int p = 0; p < 2; p++) {
            gl_lds16(aptr0 + kc + p * 32, &As[lb + p * 4096]);
            gl_lds16(aptr1 + kc + p * 32, &As[lb + p * 4096 + 512]);
            gl_lds16(bptr0 + kc + p * 32, &Bs[lb + p * 4096]);
            gl_lds16(bptr1 + kc + p * 32, &Bs[lb + p * 4096 + 512]);
        }
    };
    auto compute = [&](int buf) {
        #pragma unroll
        for (int p = 0; p < 2; p++) {
            short8_t af[4], bfr[4];
            #pragma unroll
            for (int i = 0; i < 4; i++)
                af[i] = *(const short8_t*)&As[buf * 8192 + p * 4096 + (wm + i * 16 + frow) * 32 + fswz];
            #pragma unroll
            for (int j = 0; j < 4; j++)
                bfr[j] = *(const short8_t*)&Bs[buf * 8192 + p * 4096 + (wn + j * 16 + frow) * 32 + fswz];
            #pragma unroll
            for (int i = 0; i < 4; i++)
                #pragma unroll
                for (int j = 0; j < 4; j++)
                    acc[i][j] = __builtin_amdgcn_mfma_f32_16x16x32_bf16(af[i], bfr[j], acc[i][j], 0, 0, 0);
        }
    };

    constexpr int NK = K / 64;
    stage(0, 0);
    __syncthreads();                       // drains prologue vmcnt
    #pragma unroll 2
    for (int tk = 0; tk < NK - 1; ++tk) {
        stage((tk + 1) & 1, (tk + 1) * 64);   // issue next tile before compute
        compute(tk & 1);
        __syncthreads();                      // one barrier/K-tile: vmcnt(0)+lgkmcnt(0) drain
    }
    compute((NK - 1) & 1);                    // peeled last tile (no prefetch)

    int quad = lane >> 4;
    int colb = lane & 15;
    float bv[4];
    #pragma unroll
    for (int j = 0; j < 4; j++) bv[j] = bias[(size_t)e * N + n0 + wn + j * 16 + colb];

    if constexpr (sizeof(OutT) == 2) {
        unsigned short* cbuf = As;   // reuse staging LDS (k-loop fully drained by barrier below)
        #pragma unroll
        for (int p = 0; p < 2; p++) {
            __syncthreads();
            if ((wave >> 1) == p) {
                #pragma unroll
                for (int i = 0; i < 4; i++)
                    #pragma unroll
                    for (int j = 0; j < 4; j++)
                        #pragma unroll
                        for (int r = 0; r < 4; r++) {
                            float v = acc[i][j][r] + bv[j];
                            if (RELU) v = fmaxf(v, 0.0f);
                            int wrow = wm + i * 16 + quad * 4 + r;
                            // XOR de-conflict: 32B slot flip on row bit 3 -> quad bank
                            // windows {0,64,32,96} mod 128, conflict-free u16 stores
                            int cc = (j * 16 + colb) ^ (((wrow >> 3) & 1) * 16);
                            cbuf[wrow * 72 + cc] = f2bf(v);
                        }
            }
            __syncthreads();
            int row = tid >> 1, ch = (tid & 1) * 32;
            int grow = m0 + row;
            if (grow < seg1) {
                #pragma unroll
                for (int k = 0; k < 4; k++) {
                    int vv = (ch + k * 8) ^ (((row >> 3) & 1) * 16);
                    short8_t v = *(const short8_t*)&cbuf[row * 72 + vv];
                    *(short8_t*)&C[(size_t)grow * N + n0 + p * 64 + ch + k * 8] = v;
                }
            }
        }
    } else {
        #pragma unroll
        for (int i = 0; i < 4; i++) {
            #pragma unroll
            for (int j = 0; j < 4; j++) {
                int col = n0 + wn + j * 16 + colb;
                #pragma unroll
                for (int r = 0; r < 4; r++) {
                    int row = m0 + wm + i * 16 + quad * 4 + r;
                    if (row < seg1) {
                        float v = acc[i][j][r] + bv[j];
                        if (RELU) v = fmaxf(v, 0.0f);
                        C[(size_t)row * N + col] = v;
                    }
                }
            }
        }
    }
}

extern "C" void kernel_launch(void* const* d_in, const int* in_sizes, int n_in,
                              void* d_out, int out_size, void* d_ws, size_t ws_size,
                              hipStream_t stream) {
    const float* x  = (const float*)d_in[0];
    const float* Wg = (const float*)d_in[1];
    const float* bg = (const float*)d_in[2];
    const float* W1 = (const float*)d_in[3];
    const float* b1 = (const float*)d_in[4];
    const float* W2 = (const float*)d_in[5];
    const float* b2 = (const float*)d_in[6];
    float* out = (float*)d_out;

    char* ws = (char*)d_ws;
    size_t off = 0;
    auto alloc = [&](size_t bytes) -> char* {
        char* p = ws + off;
        off += (bytes + 255) & ~(size_t)255;
        return p;
    };
    unsigned short* W1T = (unsigned short*)alloc((size_t)NEXP * DDIM * FFDIM * 2);  // [E][FF][D]
    unsigned short* W2T = (unsigned short*)alloc((size_t)NEXP * DDIM * FFDIM * 2);  // [E][D][FF]
    unsigned short* Xs  = (unsigned short*)alloc((size_t)TTOK * DDIM * 2);          // sorted tokens
    unsigned short* H   = (unsigned short*)alloc((size_t)TTOK * FFDIM * 2);         // hidden
    int*   route        = (int*)alloc((size_t)TTOK * 4);
    float* pmaxArr      = (float*)alloc((size_t)TTOK * 4);
    int*   blockCounts  = (int*)alloc((size_t)NGB * NEXP * 4);
    int*   blockOffsets = (int*)alloc((size_t)NGB * NEXP * 4);
    int*   segPrefix    = (int*)alloc((size_t)(NEXP + 1) * 4);
    int*   tilePrefix   = (int*)alloc((size_t)(NEXP + 1) * 4);

    // 1: both weight transposes + bf16 cast (R5 32x32 version)
    transpose_cvt2<<<dim3(1024, 1, 2 * NEXP), 256, 0, stream>>>(W1, W2, W1T, W2T);
    // 2: gating (1024 blocks)
    gate_kernel<<<NGB, 256, 0, stream>>>(x, Wg, bg, route, pmaxArr, blockCounts);
    // 3: scan -> stable sort offsets + tile lists
    scan_kernel<<<1, NGB, 0, stream>>>(blockCounts, blockOffsets, segPrefix, tilePrefix);
    // 4: permute + scale + cast tokens (1024 blocks)
    scatter_kernel<<<NGB, 256, 0, stream>>>(x, route, pmaxArr, blockOffsets, Xs);
    // 5: H = relu(Xs @ W1[e] + b1[e])  (bf16), 128x128 tiles, m-fastest grid (136, 16)
    gemm_seg<true, unsigned short, DDIM, FFDIM><<<dim3(MAXTILES, FFDIM / 128, 1), 256, 0, stream>>>(
        Xs, W1T, b1, H, segPrefix, tilePrefix);
    // 6: out = H @ W2[e] + b2[e]  (fp32), 128x128 tiles, m-fastest grid (136, 4)
    gemm_seg<false, float, FFDIM, DDIM><<<dim3(MAXTILES, DDIM / 128, 1), 256, 0, stream>>>(
        H, W2T, b2, out, segPrefix, tilePrefix);
}

// Round 2
// 310.349 us; speedup vs baseline: 1.1007x; 1.1007x over previous
//
#include <hip/hip_runtime.h>
#include <hip/hip_bf16.h>

constexpr int TTOK  = 16384;   // B*S = 8*2048
constexpr int DDIM  = 512;
constexpr int FFDIM = 2048;
constexpr int NEXP  = 8;
constexpr int GB_TOK = 16;             // tokens per gate/scatter block
constexpr int NGB    = TTOK / GB_TOK;  // 1024
constexpr int MAXTILES = TTOK / 128 + NEXP;  // 136: worst-case 128-row M-tiles (GEMM2)
constexpr int MT256    = TTOK / 256 + NEXP;  // 72: worst-case 256-row M-tiles (GEMM1), 72%8==0

typedef __attribute__((ext_vector_type(8))) short short8_t;
typedef __attribute__((ext_vector_type(4))) float f32x4_t;

__device__ __forceinline__ unsigned short f2bf(float f) {
    union { float f; unsigned u; } v; v.f = f;
    return (unsigned short)((v.u + 0x7fffu + ((v.u >> 16) & 1u)) >> 16);  // RNE
}

__device__ __forceinline__ void gl_lds16(const void* g, void* l) {
    __builtin_amdgcn_global_load_lds(
        (const __attribute__((address_space(1))) void*)g,
        (__attribute__((address_space(3))) void*)l,
        16, 0, 0);
}

// ---------------- transpose + fp32->bf16 cast:  src [E][R][C] f32 -> dst [E][C][R] bf16
__global__ __launch_bounds__(256) void transpose_cvt2(const float* __restrict__ W1,
                                                      const float* __restrict__ W2,
                                                      unsigned short* __restrict__ W1T,
                                                      unsigned short* __restrict__ W2T) {
    __shared__ float tile[32][33];
    int z = blockIdx.z;
    bool isW2 = z >= NEXP;
    int e = isW2 ? z - NEXP : z;
    int R = isW2 ? FFDIM : DDIM;
    int C = isW2 ? DDIM : FFDIM;
    int tilesC = C / 32;
    int t = blockIdx.x;
    int c0 = (t % tilesC) * 32;
    int r0 = (t / tilesC) * 32;
    const float* s = (isW2 ? W2 : W1) + (size_t)e * DDIM * FFDIM;
    unsigned short* d = (isW2 ? W2T : W1T) + (size_t)e * DDIM * FFDIM;
    int tx = threadIdx.x & 31, ty = threadIdx.x >> 5;   // 32 x 8
    #pragma unroll
    for (int i = 0; i < 4; i++)
        tile[ty + 8 * i][tx] = s[(size_t)(r0 + ty + 8 * i) * C + c0 + tx];
    __syncthreads();
    #pragma unroll
    for (int i = 0; i < 4; i++)
        d[(size_t)(c0 + ty + 8 * i) * R + r0 + tx] = f2bf(tile[tx][ty + 8 * i]);
}

// ---------------- gating: Wg in registers, f64 accum, 1024 blocks x 16 tokens
__global__ __launch_bounds__(256) void gate_kernel(const float* __restrict__ x,
                                                   const float* __restrict__ Wg,
                                                   const float* __restrict__ bg,
                                                   int* __restrict__ route,
                                                   float* __restrict__ pmax,
                                                   int* __restrict__ blockCounts) {
    __shared__ int cnt[NEXP];
    __shared__ float bgs[NEXP];
    int tid = threadIdx.x;
    if (tid < NEXP) { cnt[tid] = 0; bgs[tid] = bg[tid]; }
    __syncthreads();
    int wave = tid >> 6, lane = tid & 63;
    float w[8][8];
    #pragma unroll
    for (int jj = 0; jj < 8; jj++) {
        float4 a = *(const float4*)(Wg + (size_t)(lane * 8 + jj) * NEXP);
        float4 b = *(const float4*)(Wg + (size_t)(lane * 8 + jj) * NEXP + 4);
        w[jj][0] = a.x; w[jj][1] = a.y; w[jj][2] = a.z; w[jj][3] = a.w;
        w[jj][4] = b.x; w[jj][5] = b.y; w[jj][6] = b.z; w[jj][7] = b.w;
    }
    int tbase = blockIdx.x * GB_TOK + wave * 4;
    for (int it = 0; it < 4; it++) {
        int t = tbase + it;
        float4 xa = *(const float4*)(x + (size_t)t * DDIM + lane * 8);
        float4 xb = *(const float4*)(x + (size_t)t * DDIM + lane * 8 + 4);
        float xs[8] = {xa.x, xa.y, xa.z, xa.w, xb.x, xb.y, xb.z, xb.w};
        double acc[NEXP];
        #pragma unroll
        for (int e = 0; e < NEXP; e++) acc[e] = 0.0;
        #pragma unroll
        for (int jj = 0; jj < 8; jj++) {
            double xv = (double)xs[jj];
            #pragma unroll
            for (int e = 0; e < NEXP; e++) acc[e] += xv * (double)w[jj][e];
        }
        #pragma unroll
        for (int off = 32; off > 0; off >>= 1) {
            #pragma unroll
            for (int e = 0; e < NEXP; e++) acc[e] += __shfl_down(acc[e], off);
        }
        if (lane == 0) {
            double l[NEXP];
            #pragma unroll
            for (int e = 0; e < NEXP; e++) l[e] = acc[e] + (double)bgs[e];
            int r = 0; double lm = l[0];
            #pragma unroll
            for (int e = 1; e < NEXP; e++) if (l[e] > lm) { lm = l[e]; r = e; }
            double s = 0.0;
            #pragma unroll
            for (int e = 0; e < NEXP; e++) s += exp(l[e] - lm);
            route[t] = r;
            pmax[t] = (float)(1.0 / s);
            atomicAdd(&cnt[r], 1);
        }
    }
    __syncthreads();
    if (tid < NEXP) blockCounts[blockIdx.x * NEXP + tid] = cnt[tid];
}

// ---------------- single-block scan -> stable counting-sort offsets + tile lists (128 & 256)
__global__ __launch_bounds__(1024) void scan_kernel(const int* __restrict__ blockCounts,
                                                    int* __restrict__ blockOffsets,
                                                    int* __restrict__ segPrefix,
                                                    int* __restrict__ tilePrefix,
                                                    int* __restrict__ tilePrefix2) {
    __shared__ int sc[NGB][NEXP];
    __shared__ int base[NEXP + 1];
    int b = threadIdx.x;
    int c[NEXP];
    #pragma unroll
    for (int e = 0; e < NEXP; e++) { c[e] = blockCounts[b * NEXP + e]; sc[b][e] = c[e]; }
    __syncthreads();
    for (int off = 1; off < NGB; off <<= 1) {
        int t[NEXP];
        if (b >= off) {
            #pragma unroll
            for (int e = 0; e < NEXP; e++) t[e] = sc[b - off][e];
        }
        __syncthreads();
        if (b >= off) {
            #pragma unroll
            for (int e = 0; e < NEXP; e++) sc[b][e] += t[e];
        }
        __syncthreads();
    }
    if (b == 0) {
        int s = 0;
        #pragma unroll
        for (int e = 0; e < NEXP; e++) { base[e] = s; s += sc[NGB - 1][e]; }
        base[NEXP] = s;
        for (int e = 0; e <= NEXP; e++) segPrefix[e] = base[e];
        int tp = 0, tp2 = 0;
        tilePrefix[0] = 0; tilePrefix2[0] = 0;
        for (int e = 0; e < NEXP; e++) {
            tp  += (sc[NGB - 1][e] + 127) / 128;
            tp2 += (sc[NGB - 1][e] + 255) / 256;
            tilePrefix[e + 1] = tp;
            tilePrefix2[e + 1] = tp2;
        }
    }
    __syncthreads();
    #pragma unroll
    for (int e = 0; e < NEXP; e++)
        blockOffsets[b * NEXP + e] = base[e] + sc[b][e] - c[e];
}

// ---------------- scatter: Xs[dst(t)] = bf16(x[t] * pmax[t]), expert-sorted stable order
__global__ __launch_bounds__(256) void scatter_kernel(const float* __restrict__ x,
                                                      const int* __restrict__ route,
                                                      const float* __restrict__ pmax,
                                                      const int* __restrict__ blockOffsets,
                                                      unsigned short* __restrict__ Xs) {
    __shared__ int dstL[GB_TOK];
    __shared__ float pmL[GB_TOK];
    int tid = threadIdx.x;
    int bb = blockIdx.x;
    if (tid < GB_TOK) {
        int t = bb * GB_TOK + tid;
        int r = route[t];
        unsigned long long ltmask = (tid == 0) ? 0ull : ((~0ull) >> (64 - tid));
        int rank = 0;
        #pragma unroll
        for (int e = 0; e < NEXP; e++) {
            unsigned long long m = __ballot(r == e);
            if (r == e) rank = __popcll(m & ltmask);
        }
        dstL[tid] = blockOffsets[bb * NEXP + r] + rank;
        pmL[tid] = pmax[t];
    }
    __syncthreads();
    int wave = tid >> 6, lane = tid & 63;
    for (int rr = 0; rr < 4; rr++) {
        int rowl = wave * 4 + rr;
        int t = bb * GB_TOK + rowl;
        float pm = pmL[rowl];
        const float4* xr = (const float4*)(x + (size_t)t * DDIM) + lane * 2;
        float4 a = xr[0], b = xr[1];
        union { short8_t v; unsigned short s[8]; } o;
        o.s[0] = f2bf(a.x * pm); o.s[1] = f2bf(a.y * pm);
        o.s[2] = f2bf(a.z * pm); o.s[3] = f2bf(a.w * pm);
        o.s[4] = f2bf(b.x * pm); o.s[5] = f2bf(b.y * pm);
        o.s[6] = f2bf(b.z * pm); o.s[7] = f2bf(b.w * pm);
        *(short8_t*)(Xs + (size_t)dstL[rowl] * DDIM + lane * 8) = o.v;
    }
}

// ============================================================================
// GEMM1: 256x256 tile, BK=64, 8 waves (2M x 4N), 8-phase schedule with counted
// vmcnt (T3+T4), st_16x32 LDS swizzle (T2, both-sides per rule 21), setprio (T5),
// XCD-chunked grid (T1). K=512 (NK=8), N=2048, bf16 out with ReLU+bias.
//
// Per-wave output 128x64 spread across halves: i<4 -> A-half0, i>=4 -> A-half1;
// j<2 -> B-half0, j>=2 -> B-half1. Phases per K-tile consume quadrants
// (A0,B0),(A0,B1),(A1,B1),(A1,B0); staging runs 3-6 phases ahead:
//   p0: stage A1(t+1)   p1: stage B0(t+1)   p2: stage A0(t+2)   p3: stage B1(t+2)
// => at each tile boundary exactly 2 half-tiles (4 loads/thread) are in flight
// => s_waitcnt vmcnt(4), never a drain (except tail where t+2>=NK -> vmcnt(0)).
// Safety: each half's last ds_read is >=2 barriers before its re-stage issue.
// ============================================================================
__global__ __launch_bounds__(512, 2) void gemm1_8ph(const unsigned short* __restrict__ A,
                                                    const unsigned short* __restrict__ Bt,
                                                    const float* __restrict__ bias,
                                                    unsigned short* __restrict__ C,
                                                    const int* __restrict__ segPrefix,
                                                    const int* __restrict__ tileP2) {
    constexpr int K = 512, N = 2048, NK = K / 64;
    int bx = blockIdx.x;
    bx = (bx & 7) * (MT256 / 8) + (bx >> 3);      // bijective XCD chunking (72 % 8 == 0)
    if (bx >= tileP2[NEXP]) return;               // block-uniform
    int e = 0;
    #pragma unroll
    for (int i = 1; i <= NEXP; i++) e += (bx >= tileP2[i]) ? 1 : 0;
    int seg1 = segPrefix[e + 1];
    int m0 = segPrefix[e] + (bx - tileP2[e]) * 256;
    int n0 = blockIdx.y * 256;

    // A: [buf2][half2][128 rows][64 cols] bf16 = 64 KiB at shorts [0, 32768)
    // B: same at [32768, 65536). Total 128 KiB.
    __shared__ __align__(16) unsigned short SH[65536];

    int tid = threadIdx.x, wave = tid >> 6, lane = tid & 63;
    int wm = wave >> 2, wn = wave & 3;            // 2M x 4N wave grid
    int frow = lane & 15, gr = lane >> 4;
    const unsigned short* Bte = Bt + (size_t)e * N * K;

    // -- staging source pointers (pre-swizzled global source; gl_lds dest linear)
    // dest(linear) L = q*1024 + lane*16 within a 16 KiB half; content at L must be
    // the element at swz(L), swz: byte ^= ((byte>>9)&1)<<5 (st_16x32). rh unaffected.
    const unsigned short* aS[2][2];   // [half][r]
    const unsigned short* bS[2][2];
    #pragma unroll
    for (int r = 0; r < 2; r++) {
        int q = wave * 2 + r;
        int Lr = q * 1024 + lane * 16;
        int rh = Lr >> 7;                               // row within half (0..127)
        int cb = (Lr & 127) ^ (((Lr >> 9) & 1) << 5);   // swizzled col byte
        #pragma unroll
        for (int h = 0; h < 2; h++) {
            int arow = m0 + h * 128 + rh; arow = arow < TTOK ? arow : TTOK - 1;
            aS[h][r] = A + (size_t)arow * K + (cb >> 1);
            bS[h][r] = Bte + (size_t)(n0 + h * 128 + rh) * K + (cb >> 1);
        }
    }

    f32x4_t acc[8][4];
    #pragma unroll
    for (int i = 0; i < 8; i++)
        #pragma unroll
        for (int j = 0; j < 4; j++) acc[i][j] = (f32x4_t){0.f, 0.f, 0.f, 0.f};

    short8_t aR[4][2];        // current A-half frags [i4][ks]
    short8_t bR[2][2][2];     // both B-halves live  [jh][jq][ks]

    auto BAR = [] {
        asm volatile("" ::: "memory");
        __builtin_amdgcn_s_barrier();
        asm volatile("" ::: "memory");
    };
    auto stA = [&](int bufd, int h, int kc) {
        #pragma unroll
        for (int r = 0; r < 2; r++)
            gl_lds16(aS[h][r] + kc, &SH[(bufd * 2 + h) * 8192 + (wave * 2 + r) * 512]);
    };
    auto stB = [&](int bufd, int h, int kc) {
        #pragma unroll
        for (int r = 0; r < 2; r++)
            gl_lds16(bS[h][r] + kc, &SH[32768 + (bufd * 2 + h) * 8192 + (wave * 2 + r) * 512]);
    };
    auto off = [&](int buf, int h, int rh, int ks) {
        int b = rh * 128 + ks * 64 + gr * 16;
        b ^= ((b >> 9) & 1) << 5;                 // same involution as staging source
        return (buf * 2 + h) * 8192 + (b >> 1);
    };
    auto ldA = [&](int buf, int ih) {
        #pragma unroll
        for (int i4 = 0; i4 < 4; i4++)
            #pragma unroll
            for (int ks = 0; ks < 2; ks++)
                aR[i4][ks] = *(const short8_t*)&SH[off(buf, ih, wm * 64 + i4 * 16 + frow, ks)];
    };
    auto ldB = [&](int buf, int jh) {
        #pragma unroll
        for (int jq = 0; jq < 2; jq++)
            #pragma unroll
            for (int ks = 0; ks < 2; ks++)
                bR[jh][jq][ks] = *(const short8_t*)&SH[32768 + off(buf, jh, wn * 32 + jq * 16 + frow, ks)];
    };
    auto mm = [&](int ih, int jh) {
        __builtin_amdgcn_s_setprio(1);
        #pragma unroll
        for (int i4 = 0; i4 < 4; i4++)
            #pragma unroll
            for (int jq = 0; jq < 2; jq++)
                #pragma unroll
                for (int ks = 0; ks < 2; ks++)
                    acc[ih * 4 + i4][jh * 2 + jq] = __builtin_amdgcn_mfma_f32_16x16x32_bf16(
                        aR[i4][ks], bR[jh][jq][ks], acc[ih * 4 + i4][jh * 2 + jq], 0, 0, 0);
        __builtin_amdgcn_s_setprio(0);
    };

    // -- prologue: tile0's 4 halves, then tile1's lead pair; leave 4 loads in flight
    stA(0, 0, 0); stB(0, 1, 0); stA(0, 1, 0); stB(0, 0, 0);
    stA(1, 0, 64); stB(1, 1, 64);
    asm volatile("s_waitcnt vmcnt(4)" ::: "memory");
    BAR();

    #pragma unroll 2
    for (int t = 0; t < NK; ++t) {
        const int bc = t & 1;
        // phase 0: quadrant (A0, B0)
        ldA(bc, 0); ldB(bc, 0);
        if (t + 1 < NK) stA(bc ^ 1, 1, (t + 1) * 64);
        BAR(); mm(0, 0); BAR();
        // phase 1: (A0, B1)
        ldB(bc, 1);
        if (t + 1 < NK) stB(bc ^ 1, 0, (t + 1) * 64);
        BAR(); mm(0, 1); BAR();
        // phase 2: (A1, B1)
        ldA(bc, 1);
        if (t + 2 < NK) stA(bc, 0, (t + 2) * 64);
        BAR(); mm(1, 1); BAR();
        // phase 3: (A1, B0)
        if (t + 2 < NK) stB(bc, 1, (t + 2) * 64);
        BAR(); mm(1, 0);
        if (t + 1 < NK) {
            if (t + 2 < NK) asm volatile("s_waitcnt vmcnt(4)" ::: "memory");
            else            asm volatile("s_waitcnt vmcnt(0)" ::: "memory");
        }
        BAR();
    }

    // -- epilogue: bias + ReLU + bf16, staged through LDS for coalesced short8 stores
    float bvv[2][2];
    #pragma unroll
    for (int jh = 0; jh < 2; jh++)
        #pragma unroll
        for (int jq = 0; jq < 2; jq++)
            bvv[jh][jq] = bias[(size_t)e * N + n0 + jh * 128 + wn * 32 + jq * 16 + frow];

    unsigned short* cbuf = SH;   // 256 rows x 136 stride = 34816 shorts (fits)
    #pragma unroll
    for (int p = 0; p < 2; p++) {   // column half p = jh
        __syncthreads();
        #pragma unroll
        for (int i = 0; i < 8; i++)
            #pragma unroll
            for (int jq = 0; jq < 2; jq++)
                #pragma unroll
                for (int rr = 0; rr < 4; rr++) {
                    int row = (i >> 2) * 128 + wm * 64 + (i & 3) * 16 + gr * 4 + rr;
                    int col = wn * 32 + jq * 16 + frow;
                    float v = acc[i][p * 2 + jq][rr] + bvv[p][jq];
                    v = fmaxf(v, 0.0f);
                    cbuf[row * 136 + col] = f2bf(v);
                }
        __syncthreads();
        int row = tid >> 1, part = tid & 1;
        int grow = m0 + row;
        if (grow < seg1) {
            #pragma unroll
            for (int c = 0; c < 8; c++) {
                short8_t v = *(const short8_t*)&cbuf[row * 136 + part * 64 + c * 8];
                *(short8_t*)&C[(size_t)grow * N + n0 + p * 128 + part * 64 + c * 8] = v;
            }
        }
    }
}

// ---------------- GEMM2 (R0-proven): 128x128 tile, BK=64, single-buffer 2-barrier,
// + XCD-chunked m-tile swizzle (136 = 8*17). fp32 out.
template <bool RELU, typename OutT, int K, int N>
__global__ __launch_bounds__(256) void gemm_seg(const unsigned short* __restrict__ A,
                                                const unsigned short* __restrict__ Bt,
                                                const float* __restrict__ bias,
                                                OutT* __restrict__ C,
                                                const int* __restrict__ segPrefix,
                                                const int* __restrict__ tilePrefix) {
    int bx = blockIdx.x;
    bx = (bx & 7) * (MAXTILES / 8) + (bx >> 3);   // bijective XCD chunking (136 % 8 == 0)
    int t = bx;
    if (t >= tilePrefix[NEXP]) return;
    int e = 0;
    #pragma unroll
    for (int i = 1; i <= NEXP; i++) e += (t >= tilePrefix[i]) ? 1 : 0;
    int seg1 = segPrefix[e + 1];
    int m0 = segPrefix[e] + (t - tilePrefix[e]) * 128;
    int n0 = blockIdx.y * 128;

    __shared__ unsigned short As[2 * 4096];
    __shared__ unsigned short Bs[2 * 4096];

    int tid = threadIdx.x, wave = tid >> 6, lane = tid & 63;
    const unsigned short* Bte = Bt + (size_t)e * N * K;

    int srow = lane >> 2;
    int sg   = (lane & 3) ^ ((lane >> 2) & 3) ^ ((lane >> 4) & 3);
    int scol = sg * 8;

    f32x4_t acc[4][4];
    #pragma unroll
    for (int i = 0; i < 4; i++)
        #pragma unroll
        for (int j = 0; j < 4; j++) acc[i][j] = (f32x4_t){0.f, 0.f, 0.f, 0.f};

    int wm = (wave & 1) * 64;
    int wn = (wave >> 1) * 64;
    int frow = lane & 15;
    int gr = lane >> 4;
    int fswz = (gr ^ (frow & 3) ^ ((frow >> 2) & 3)) * 8;

    int reg0 = wave * 2;
    int arow0 = m0 + reg0 * 16 + srow;
    arow0 = arow0 < TTOK ? arow0 : TTOK - 1;
    int arow1 = m0 + (reg0 + 1) * 16 + srow;
    arow1 = arow1 < TTOK ? arow1 : TTOK - 1;
    const unsigned short* aptr0 = A + (size_t)arow0 * K + scol;
    const unsigned short* aptr1 = A + (size_t)arow1 * K + scol;
    const unsigned short* bptr0 = Bte + (size_t)(n0 + reg0 * 16 + srow) * K + scol;
    const unsigned short* bptr1 = Bte + (size_t)(n0 + (reg0 + 1) * 16 + srow) * K + scol;

    #pragma unroll
    for (int kc = 0; kc < K; kc += 64) {
        #pragma unroll
        for (int p = 0; p < 2; p++) {
            gl_lds16(aptr0 + kc + p * 32, &As[p * 4096 + reg0 * 512]);
            gl_lds16(aptr1 + kc + p * 32, &As[p * 4096 + (reg0 + 1) * 512]);
            gl_lds16(bptr0 + kc + p * 32, &Bs[p * 4096 + reg0 * 512]);
            gl_lds16(bptr1 + kc + p * 32, &Bs[p * 4096 + (reg0 + 1) * 512]);
        }
        __syncthreads();
        #pragma unroll
        for (int p = 0; p < 2; p++) {
            short8_t af[4], bfr[4];
            #pragma unroll
            for (int i = 0; i < 4; i++)
                af[i] = *(const short8_t*)&As[p * 4096 + (wm + i * 16 + frow) * 32 + fswz];
            #pragma unroll
            for (int j = 0; j < 4; j++)
                bfr[j] = *(const short8_t*)&Bs[p * 4096 + (wn + j * 16 + frow) * 32 + fswz];
            #pragma unroll
            for (int i = 0; i < 4; i++)
                #pragma unroll
                for (int j = 0; j < 4; j++)
                    acc[i][j] = __builtin_amdgcn_mfma_f32_16x16x32_bf16(af[i], bfr[j], acc[i][j], 0, 0, 0);
        }
        __syncthreads();
    }

    int quad = lane >> 4;
    int colb = lane & 15;
    float bv[4];
    #pragma unroll
    for (int j = 0; j < 4; j++) bv[j] = bias[(size_t)e * N + n0 + wn + j * 16 + colb];

    #pragma unroll
    for (int i = 0; i < 4; i++) {
        #pragma unroll
        for (int j = 0; j < 4; j++) {
            int col = n0 + wn + j * 16 + colb;
            #pragma unroll
            for (int r = 0; r < 4; r++) {
                int row = m0 + wm + i * 16 + quad * 4 + r;
                if (row < seg1) {
                    float v = acc[i][j][r] + bv[j];
                    if (RELU) v = fmaxf(v, 0.0f);
                    C[(size_t)row * N + col] = v;
                }
            }
        }
    }
}

extern "C" void kernel_launch(void* const* d_in, const int* in_sizes, int n_in,
                              void* d_out, int out_size, void* d_ws, size_t ws_size,
                              hipStream_t stream) {
    const float* x  = (const float*)d_in[0];
    const float* Wg = (const float*)d_in[1];
    const float* bg = (const float*)d_in[2];
    const float* W1 = (const float*)d_in[3];
    const float* b1 = (const float*)d_in[4];
    const float* W2 = (const float*)d_in[5];
    const float* b2 = (const float*)d_in[6];
    float* out = (float*)d_out;

    char* ws = (char*)d_ws;
    size_t off = 0;
    auto alloc = [&](size_t bytes) -> char* {
        char* p = ws + off;
        off += (bytes + 255) & ~(size_t)255;
        return p;
    };
    unsigned short* W1T = (unsigned short*)alloc((size_t)NEXP * DDIM * FFDIM * 2);  // [E][FF][D]
    unsigned short* W2T = (unsigned short*)alloc((size_t)NEXP * DDIM * FFDIM * 2);  // [E][D][FF]
    unsigned short* Xs  = (unsigned short*)alloc((size_t)TTOK * DDIM * 2);          // sorted tokens
    unsigned short* H   = (unsigned short*)alloc((size_t)TTOK * FFDIM * 2);         // hidden
    int*   route        = (int*)alloc((size_t)TTOK * 4);
    float* pmaxArr      = (float*)alloc((size_t)TTOK * 4);
    int*   blockCounts  = (int*)alloc((size_t)NGB * NEXP * 4);
    int*   blockOffsets = (int*)alloc((size_t)NGB * NEXP * 4);
    int*   segPrefix    = (int*)alloc((size_t)(NEXP + 1) * 4);
    int*   tilePrefix   = (int*)alloc((size_t)(NEXP + 1) * 4);
    int*   tilePrefix2  = (int*)alloc((size_t)(NEXP + 1) * 4);

    // 1: both weight transposes + bf16 cast
    transpose_cvt2<<<dim3(1024, 1, 2 * NEXP), 256, 0, stream>>>(W1, W2, W1T, W2T);
    // 2: gating
    gate_kernel<<<NGB, 256, 0, stream>>>(x, Wg, bg, route, pmaxArr, blockCounts);
    // 3: scan -> stable sort offsets + tile lists (128- and 256-granular)
    scan_kernel<<<1, NGB, 0, stream>>>(blockCounts, blockOffsets, segPrefix, tilePrefix, tilePrefix2);
    // 4: permute + scale + cast tokens
    scatter_kernel<<<NGB, 256, 0, stream>>>(x, route, pmaxArr, blockOffsets, Xs);
    // 5: H = relu(Xs @ W1[e] + b1[e])  (bf16) — 8-phase 256x256 pipeline, grid (72, 8)
    gemm1_8ph<<<dim3(MT256, FFDIM / 256, 1), 512, 0, stream>>>(
        Xs, W1T, b1, H, segPrefix, tilePrefix2);
    // 6: out = H @ W2[e] + b2[e]  (fp32) — proven 128x128 kernel + XCD swizzle, grid (136, 4)
    gemm_seg<false, float, FFDIM, DDIM><<<dim3(MAXTILES, DDIM / 128, 1), 256, 0, stream>>>(
        H, W2T, b2, out, segPrefix, tilePrefix);
}